// Round 9
// baseline (97.451 us; speedup 1.0000x reference)
//
#include <hip/hip_runtime.h>
#include <hip/hip_bf16.h>

#define BB 64
#define TT 1024
#define NN 512
#define LISTCAP (1u << 18)

static constexpr float THR = 0.15f;

typedef __attribute__((ext_vector_type(8))) short bf16x8;
typedef __attribute__((ext_vector_type(4))) float f32x4;

// async global->LDS, 16B per lane; dest = wave-uniform base + lane*16 (HW rule)
__device__ __forceinline__ void gload16(const void* g, void* lds_dst) {
    __builtin_amdgcn_global_load_lds(
        (const __attribute__((address_space(1))) unsigned int*)g,
        (__attribute__((address_space(3))) unsigned int*)lds_dst, 16, 0, 0);
}

// ---------------- kernel T: fused colsum + fp32->bf16 transpose ----------------
// (verified r6-r8, HBM-roofline-bound ~33us). Produces xbf[b][col][t] bf16 RTZ,
// t contiguous, plus s1, dv, nv=||x||, nl=||l|| per column. Zeroes fired/cnt.
__global__ __launch_bounds__(512) void transpose_colsum(
    const float* __restrict__ x, ushort* __restrict__ xbf,
    float* __restrict__ s1, float* __restrict__ dv,
    float* __restrict__ nv, float* __restrict__ nl,
    unsigned* __restrict__ fired, unsigned* __restrict__ cnt) {
    __shared__ ushort tile[64 * 512];       // 64 KiB
    __shared__ float red[3][8][64];         // 6 KiB
    int b = blockIdx.x, ng = blockIdx.y;
    int n0 = ng * 64;
    int tid = threadIdx.x, w = tid >> 6, l = tid & 63;
    const float* xb = x + (size_t)b * TT * NN;
    float a1 = 0.f, a2 = 0.f, al = 0.f;
    unsigned swz = ((unsigned)l & 7u) << 4;

    if (b == 0 && ng == 0 && tid == 64) *cnt = 0;

    for (int tc = 0; tc < 2; ++tc) {
        for (int i = 0; i < 8; ++i) {
            int tl0 = i * 64 + w * 8;
            int t0 = tc * 512 + tl0;
            unsigned hp[4];
            #pragma unroll
            for (int q = 0; q < 4; ++q) {
                float v0 = xb[(size_t)(t0 + 2 * q) * NN + n0 + l];
                float v1 = xb[(size_t)(t0 + 2 * q + 1) * NN + n0 + l];
                a1 += v0 + v1;
                a2 += v0 * v0 + v1 * v1;
                unsigned u0 = __float_as_uint(v0), u1 = __float_as_uint(v1);
                float h0 = __uint_as_float(u0 & 0xFFFF0000u);
                float h1 = __uint_as_float(u1 & 0xFFFF0000u);
                float l0 = v0 - h0, l1 = v1 - h1;   // exact residuals
                al += l0 * l0 + l1 * l1;
                hp[q] = (u0 >> 16) | (u1 & 0xFFFF0000u);
            }
            unsigned off = (unsigned)l * 1024u + (((unsigned)tl0 * 2u) ^ swz);
            *(uint4*)((char*)tile + off) = make_uint4(hp[0], hp[1], hp[2], hp[3]);
        }
        __syncthreads();
        #pragma unroll
        for (int cc = 0; cc < 8; ++cc) {
            int cl = w * 8 + cc;
            unsigned src = (unsigned)cl * 1024u
                           + (((unsigned)l * 16u) ^ (((unsigned)cl & 7u) << 4));
            uint4 val = *(const uint4*)((char*)tile + src);
            ushort* dst = xbf + ((size_t)(b * NN + n0 + cl) * TT + tc * 512 + l * 8);
            *(uint4*)dst = val;
        }
        __syncthreads();
    }
    red[0][w][l] = a1; red[1][w][l] = a2; red[2][w][l] = al;
    __syncthreads();
    if (tid < 64) {
        float r1 = 0.f, r2 = 0.f, rl = 0.f;
        #pragma unroll
        for (int k = 0; k < 8; ++k) {
            r1 += red[0][k][tid]; r2 += red[1][k][tid]; rl += red[2][k][tid];
        }
        size_t o = (size_t)b * NN + n0 + tid;
        s1[o] = r1;
        dv[o] = r2 - r1 * r1 * (1.0f / TT);
        nv[o] = sqrtf(r2);
        nl[o] = sqrtf(rl);
        fired[o] = 0u;
    }
}

// ---------------- kernel B: BARRIER-FREE 1-wave MFMA SYRK ----------------
// 64x64 tile per 1-WAVE block: 36 upper tiles x 64 batches = 2304 blocks = exactly
// 9 resident/CU (LDS 9x16=144 KiB), one dispatch round, no tail. The wave owns its
// whole tile -> NO s_barrier anywhere (r0-r8 showed a ~1000+cyc/step multi-wave
// convoy no schedule could remove). Per K=32 step: s_waitcnt vmcnt(0) (own DMA) ->
// STAGE(t+1, other buf) -> 8 ds_read_b128 + 16 MFMA (0.5 reads/MFMA vs r7's 0.75).
// LDS: 2 bufs x (A 4K | B 4K), verified conflict-free layout
//   byte(col,k)=col*64+(((k>>3)^((col>>1)&3))&3)*16+(k&7)*2; DMA dest linear,
//   SOURCE pre-swizzled (rule #21): lane l covers col=16q+(l>>2),
//   k-octet kk=(l&3)^((l>>3)&3)  [(col>>1)&3 == (l>>3)&3, q-independent].
// Epilogue: r5-verified certainty bound + uncertain-pair list -> exact cleanup.
__global__ __launch_bounds__(64) void corr_mfma(
    const ushort* __restrict__ xbf, const float* __restrict__ s1,
    const float* __restrict__ dv, const float* __restrict__ nv,
    const float* __restrict__ nl, unsigned* __restrict__ fired,
    unsigned* __restrict__ cnt, unsigned* __restrict__ list) {
    __shared__ uint4 ldsbuf[1024];          // 16 KiB = 2 x (A 4K + B 4K)
    char* base = (char*)ldsbuf;

    int id = blockIdx.x;
    // XCD-chunked swizzle (2304 = 8 * 288): a batch's 36 tiles land on one XCD
    int swz = ((id & 7) * 288) + (id >> 3);
    int b = swz / 36;
    int u = swz % 36;
    int ti = 0, rem = u;
    while (rem >= (8 - ti)) { rem -= (8 - ti); ++ti; }
    int tj = ti + rem;
    int i0 = ti * 64, j0 = tj * 64;
    bool diag = (ti == tj);

    int lane = threadIdx.x & 63;
    int rl = lane & 15, kg = lane >> 4;

    // ---- staging source addresses (per-lane, pre-swizzled) ----
    int cq = lane >> 2;                          // col within 16-col chunk
    int kk = (lane & 3) ^ ((lane >> 3) & 3);     // k-octet content for this slot
    const ushort* xb = xbf + (size_t)b * NN * TT;
    const ushort* srcA = xb + (size_t)(i0 + cq) * TT + kk * 8;
    const ushort* srcB = xb + (size_t)(j0 + cq) * TT + kk * 8;

    auto STAGE = [&](int t0, int buf) {
        char* dbase = base + (buf << 13);        // *8192
        #pragma unroll
        for (int q = 0; q < 4; ++q)
            gload16(srcA + (size_t)q * 16 * TT + t0, dbase + q * 1024);
        if (!diag) {
            #pragma unroll
            for (int q = 0; q < 4; ++q)
                gload16(srcB + (size_t)q * 16 * TT + t0, dbase + 4096 + q * 1024);
        }
    };

    // ---- compute fragments: full 64x64 tile, 4 row-frags x 4 col-frags ----
    unsigned aoff[4], boff[4];
    #pragma unroll
    for (int f = 0; f < 4; ++f) {
        unsigned ca = (unsigned)(16 * f + rl);
        unsigned o = ca * 64u + ((((unsigned)kg ^ ((ca >> 1) & 3u)) & 3u) << 4);
        aoff[f] = o;
        boff[f] = o;                              // same formula, B panel offset added
    }
    unsigned bbase = diag ? 0u : 4096u;

    f32x4 acc[4][4];
    #pragma unroll
    for (int i = 0; i < 4; ++i)
        #pragma unroll
        for (int j = 0; j < 4; ++j)
            acc[i][j] = (f32x4)0.0f;

    STAGE(0, 0);
    for (int it = 0; it < 32; ++it) {
        asm volatile("s_waitcnt vmcnt(0)" ::: "memory");   // own DMA done
        __builtin_amdgcn_sched_barrier(0);                 // rule #18 fence
        if (it + 1 < 32) STAGE((it + 1) * 32, (it + 1) & 1);
        __builtin_amdgcn_sched_barrier(0);
        const char* cb = base + ((it & 1) << 13);
        bf16x8 A[4], Bv[4];
        #pragma unroll
        for (int f = 0; f < 4; ++f) A[f] = *(const bf16x8*)(cb + aoff[f]);
        #pragma unroll
        for (int f = 0; f < 4; ++f) Bv[f] = *(const bf16x8*)(cb + bbase + boff[f]);
        #pragma unroll
        for (int fj = 0; fj < 4; ++fj)
            #pragma unroll
            for (int fi = 0; fi < 4; ++fi)
                acc[fi][fj] = __builtin_amdgcn_mfma_f32_16x16x32_bf16(
                    A[fi], Bv[fj], acc[fi][fj], 0, 0, 0);
    }

    // ---- epilogue: c = acc - s1_i*s1_j/T;  lim = thr^2*d_i*d_j ----
    const float thr2 = THR * THR;
    const float invT = 1.0f / TT;
    const float* s1b = s1 + (size_t)b * NN;
    const float* dvb = dv + (size_t)b * NN;
    const float* nvb = nv + (size_t)b * NN;
    const float* nlb = nl + (size_t)b * NN;
    unsigned* fb = fired + (size_t)b * NN;
    int rowb = i0 + kg * 4;
    int colb = j0 + rl;
    #pragma unroll
    for (int fj = 0; fj < 4; ++fj) {
        int gj = colb + 16 * fj;
        float sj = s1b[gj], djv = dvb[gj];
        float nvj = nvb[gj], nlj = nlb[gj];
        #pragma unroll
        for (int fi = 0; fi < 4; ++fi) {
            int gi0 = rowb + 16 * fi;
            #pragma unroll
            for (int r = 0; r < 4; ++r) {
                int gi = gi0 + r;
                if (gj > gi) {
                    float cc = acc[fi][fj][r] - s1b[gi] * sj * invT;
                    float lim = thr2 * dvb[gi] * djv;
                    float nvi = nvb[gi], nli = nlb[gi];
                    float B = nli * nvj + nlj * nvi + 3.0f * nli * nlj
                              + 1e-3f * nvi * nvj;
                    float a = fabsf(cc);
                    float lo = a - B;
                    if (lo > 0.0f && lo * lo > lim) {
                        atomicOr(&fb[gi], 1u);
                    } else if ((a + B) * (a + B) > lim) {
                        unsigned idx = atomicAdd(cnt, 1u);
                        if (idx < LISTCAP)
                            list[idx] = ((unsigned)b << 18) | ((unsigned)gi << 9)
                                        | (unsigned)gj;
                    }
                }
            }
        }
    }
}

// ---------------- kernel B2: exact recompute of borderline pairs ----------------
__global__ __launch_bounds__(256) void cleanup_pairs(
    const float* __restrict__ x, const float* __restrict__ s1,
    const float* __restrict__ dv, const unsigned* __restrict__ cnt,
    const unsigned* __restrict__ list, unsigned* __restrict__ fired) {
    unsigned n = *cnt;
    if (n > LISTCAP) n = LISTCAP;
    int lane = threadIdx.x & 63;
    int gw = (blockIdx.x * 256 + threadIdx.x) >> 6;
    int nw = (gridDim.x * 256) >> 6;
    for (unsigned p = gw; p < n; p += nw) {
        unsigned e = list[p];
        int b = e >> 18, i = (e >> 9) & 511, j = e & 511;
        const float* xb = x + (size_t)b * TT * NN;
        double s = 0.0;
        for (int t = lane; t < TT; t += 64)
            s += (double)xb[(size_t)t * NN + i] * (double)xb[(size_t)t * NN + j];
        #pragma unroll
        for (int o = 32; o > 0; o >>= 1)
            s += __shfl_xor(s, o, 64);
        if (lane == 0) {
            double cov = s - (double)s1[(size_t)b * NN + i]
                             * (double)s1[(size_t)b * NN + j] / (double)TT;
            double lim = (double)THR * (double)THR
                         * (double)dv[(size_t)b * NN + i]
                         * (double)dv[(size_t)b * NN + j];
            if (cov * cov > lim) atomicOr(&fired[(size_t)b * NN + i], 1u);
        }
    }
}

// ---------------- kernel C: finalize mask ----------------
__global__ __launch_bounds__(512) void finalize_mask(
    const unsigned* __restrict__ fired, float* __restrict__ out) {
    int b = blockIdx.x;
    int n = threadIdx.x;
    unsigned f = fired[(size_t)b * NN + n];
    __shared__ int wsum[8];
    unsigned long long m = __ballot(f != 0u);
    int lane = n & 63;
    int w = n >> 6;
    if (lane == 0) wsum[w] = __popcll(m);
    __syncthreads();
    int cnt = 0;
    #pragma unroll
    for (int i = 0; i < 8; ++i) cnt += wsum[i];
    float val = (cnt == 0) ? 1.0f : ((cnt == 1) ? (f ? 1.0f : 0.0f) : 0.0f);
    out[(size_t)b * NN + n] = val;
}

extern "C" void kernel_launch(void* const* d_in, const int* in_sizes, int n_in,
                              void* d_out, int out_size, void* d_ws, size_t ws_size,
                              hipStream_t stream) {
    const float* x = (const float*)d_in[0];
    float* out = (float*)d_out;

    // ws layout (~66 MB)
    ushort* xbf = (ushort*)d_ws;                         // BB*NN*TT bf16 = 64 MB
    float* s1 = (float*)(xbf + (size_t)BB * NN * TT);    // B*N
    float* dv = s1 + (size_t)BB * NN;                    // B*N
    float* nv = dv + (size_t)BB * NN;                    // B*N
    float* nl = nv + (size_t)BB * NN;                    // B*N
    unsigned* fired = (unsigned*)(nl + (size_t)BB * NN); // B*N
    unsigned* cnt   = fired + (size_t)BB * NN;           // 16 (padded)
    unsigned* list  = cnt + 16;                          // LISTCAP

    transpose_colsum<<<dim3(BB, 8), 512, 0, stream>>>(x, xbf, s1, dv, nv, nl,
                                                      fired, cnt);
    corr_mfma<<<dim3(2304), 64, 0, stream>>>(xbf, s1, dv, nv, nl, fired, cnt, list);
    cleanup_pairs<<<128, 256, 0, stream>>>(x, s1, dv, cnt, list, fired);
    finalize_mask<<<BB, 512, 0, stream>>>(fired, out);
}

// Round 10
// 87.364 us; speedup vs baseline: 1.1155x; 1.1155x over previous
//
#include <hip/hip_runtime.h>
#include <hip/hip_bf16.h>

#define BB 64
#define TT 1024
#define NN 512
#define LISTCAP (1u << 18)

static constexpr float THR = 0.15f;

typedef __attribute__((ext_vector_type(8))) short bf16x8;
typedef __attribute__((ext_vector_type(4))) float f32x4;

// async global->LDS, 16B per lane; dest = wave-uniform base + lane*16 (HW rule)
__device__ __forceinline__ void gload16(const void* g, void* lds_dst) {
    __builtin_amdgcn_global_load_lds(
        (const __attribute__((address_space(1))) unsigned int*)g,
        (__attribute__((address_space(3))) unsigned int*)lds_dst, 16, 0, 0);
}

// ---------------- kernel T: fused colsum + fp32->bf16 BLOCKED transpose ----------
// Grid (BB, 8). Emits xbf[b][g][s] = 4 KiB block holding cols [64g,64g+64) x
// k [32s,32s+32) in the EXACT swizzled LDS image corr_mfma consumes:
//   byte(c,k) = c*64 + (((k>>3) ^ ((c>>1)&3))&3)*16 + (k&7)*2
// so corr's DMA is fully contiguous (src + tid*16). Swizzle baked here: thread
// (w,l) owns col l, t-octet t0=tc*512+i*64+w*8 -> s=t0>>5, koct=w&3,
// dst = base(b,g,s) + l*64 + ((koct ^ ((l>>1)&3))<<4). Also s1, dv, nv=||x||,
// nl=||l_resid|| per column; zeroes fired/cnt.
__global__ __launch_bounds__(512) void transpose_colsum(
    const float* __restrict__ x, ushort* __restrict__ xbf,
    float* __restrict__ s1, float* __restrict__ dv,
    float* __restrict__ nv, float* __restrict__ nl,
    unsigned* __restrict__ fired, unsigned* __restrict__ cnt) {
    __shared__ float red[3][8][64];
    int b = blockIdx.x, ng = blockIdx.y;
    int n0 = ng * 64;
    int tid = threadIdx.x, w = tid >> 6, l = tid & 63;
    const float* xb = x + (size_t)b * TT * NN + n0 + l;
    float a1 = 0.f, a2 = 0.f, al = 0.f;
    if (b == 0 && ng == 0 && tid == 64) *cnt = 0;

    char* xbase = (char*)xbf + ((size_t)(b * 8 + ng) * 32) * 4096
                  + (unsigned)l * 64u
                  + (((unsigned)(w & 3) ^ (((unsigned)l >> 1) & 3u)) << 4);

    for (int tc = 0; tc < 2; ++tc) {
        #pragma unroll
        for (int i = 0; i < 8; ++i) {
            int t0 = tc * 512 + i * 64 + w * 8;
            unsigned hp[4];
            #pragma unroll
            for (int q = 0; q < 4; ++q) {
                float v0 = xb[(size_t)(t0 + 2 * q) * NN];
                float v1 = xb[(size_t)(t0 + 2 * q + 1) * NN];
                a1 += v0 + v1;
                a2 += v0 * v0 + v1 * v1;
                unsigned u0 = __float_as_uint(v0), u1 = __float_as_uint(v1);
                float h0 = __uint_as_float(u0 & 0xFFFF0000u);
                float h1 = __uint_as_float(u1 & 0xFFFF0000u);
                float l0 = v0 - h0, l1 = v1 - h1;   // exact residuals
                al += l0 * l0 + l1 * l1;
                hp[q] = (u0 >> 16) | (u1 & 0xFFFF0000u);
            }
            *(uint4*)(xbase + (size_t)(t0 >> 5) * 4096) =
                make_uint4(hp[0], hp[1], hp[2], hp[3]);
        }
    }
    red[0][w][l] = a1; red[1][w][l] = a2; red[2][w][l] = al;
    __syncthreads();
    if (tid < 64) {
        float r1 = 0.f, r2 = 0.f, rl = 0.f;
        #pragma unroll
        for (int k = 0; k < 8; ++k) {
            r1 += red[0][k][tid]; r2 += red[1][k][tid]; rl += red[2][k][tid];
        }
        size_t o = (size_t)b * NN + n0 + tid;
        s1[o] = r1;
        dv[o] = r2 - r1 * r1 * (1.0f / TT);
        nv[o] = sqrtf(r2);
        nl[o] = sqrtf(rl);
        fired[o] = 0u;
    }
}

// ---------------- kernel B: FULL-OCCUPANCY MFMA SYRK ----------------
// 64x64 tile per 256-thr (4-wave) block: 36 upper tiles x 64 batches = 2304 blocks
// = 8 blocks/CU = 32 waves/CU (FULL; r0-r9 evidence: wall ~ C/(waves/CU), r7=20w,
// r9=8w). Wave-tile 32x32 (wr,wc in 2x2). LDS 16 KiB = 2 bufs x (A 4K | B 4K).
// Staging: xbf blocked layout -> ONE contiguous gload16 per thread per panel
// (1 KiB/wave-instr, perfectly coalesced; fixes r9's 64-line-per-instr scatter).
// r8's 2-phase schedule: STAGE(t+1,buf^1) -> COMPUTE(buf) -> __syncthreads.
// ds_read offsets: verified conflict-free formula (r5-r9, 0 conflicts measured).
// Epilogue: r5-verified certainty bound + uncertain-pair list -> exact cleanup.
__global__ __launch_bounds__(256, 8) void corr_mfma(
    const ushort* __restrict__ xbf, const float* __restrict__ s1,
    const float* __restrict__ dv, const float* __restrict__ nv,
    const float* __restrict__ nl, unsigned* __restrict__ fired,
    unsigned* __restrict__ cnt, unsigned* __restrict__ list) {
    __shared__ uint4 ldsbuf[1024];          // 16 KiB
    char* base = (char*)ldsbuf;

    int id = blockIdx.x;
    // XCD-chunked swizzle (2304 = 8 * 288): a batch's tiles stay on one XCD
    int swz = ((id & 7) * 288) + (id >> 3);
    int b = swz / 36;
    int u = swz % 36;
    int ti = 0, rem = u;
    while (rem >= (8 - ti)) { rem -= (8 - ti); ++ti; }
    int tj = ti + rem;
    int i0 = ti * 64, j0 = tj * 64;
    bool diag = (ti == tj);

    int tid = threadIdx.x;
    int wave = tid >> 6, lane = tid & 63;
    int rl = lane & 15, kg = lane >> 4;

    // ---- staging: contiguous blocked sources ----
    const char* srcA = (const char*)xbf + ((size_t)(b * 8 + ti) * 32) * 4096 + tid * 16;
    const char* srcB = (const char*)xbf + ((size_t)(b * 8 + tj) * 32) * 4096 + tid * 16;

    auto STAGE = [&](int s, int buf) {
        char* d = base + (buf << 13) + wave * 1024;   // wave-uniform dest
        gload16(srcA + (size_t)s * 4096, d);
        if (!diag) gload16(srcB + (size_t)s * 4096, d + 4096);
    };

    // ---- compute role: wave (wr,wc) owns rows [32wr,+32) x cols [32wc,+32) ----
    int wr = wave >> 1, wc = wave & 1;
    bool skip_mm = diag && (wr == 1) && (wc == 0);   // fully below diagonal

    unsigned aoff[2], boff[2];
    #pragma unroll
    for (int f = 0; f < 2; ++f) {
        unsigned ca = (unsigned)(32 * wr + 16 * f + rl);
        aoff[f] = ca * 64u + ((((unsigned)kg ^ ((ca >> 1) & 3u)) & 3u) << 4);
        unsigned cb2 = (unsigned)(32 * wc + 16 * f + rl);
        boff[f] = cb2 * 64u + ((((unsigned)kg ^ ((cb2 >> 1) & 3u)) & 3u) << 4);
    }
    unsigned bbase = diag ? 0u : 4096u;

    f32x4 acc[2][2];
    #pragma unroll
    for (int i = 0; i < 2; ++i)
        #pragma unroll
        for (int j = 0; j < 2; ++j)
            acc[i][j] = (f32x4)0.0f;

    STAGE(0, 0);
    __syncthreads();                         // buf0 ready (vmcnt drained)

    for (int it = 0; it < 32; ++it) {
        if (it + 1 < 32) STAGE(it + 1, (it + 1) & 1);   // in flight under compute

        const char* cb = base + ((it & 1) << 13);
        if (!skip_mm) {
            bf16x8 A[2], Bv[2];
            #pragma unroll
            for (int f = 0; f < 2; ++f) A[f] = *(const bf16x8*)(cb + aoff[f]);
            #pragma unroll
            for (int f = 0; f < 2; ++f) Bv[f] = *(const bf16x8*)(cb + bbase + boff[f]);
            #pragma unroll
            for (int fj = 0; fj < 2; ++fj)
                #pragma unroll
                for (int fi = 0; fi < 2; ++fi)
                    acc[fi][fj] = __builtin_amdgcn_mfma_f32_16x16x32_bf16(
                        A[fi], Bv[fj], acc[fi][fj], 0, 0, 0);
        }
        __syncthreads();                     // drains STAGE's vmcnt after compute
    }

    // ---- epilogue: c = acc - s1_i*s1_j/T;  lim = thr^2*d_i*d_j ----
    const float thr2 = THR * THR;
    const float invT = 1.0f / TT;
    const float* s1b = s1 + (size_t)b * NN;
    const float* dvb = dv + (size_t)b * NN;
    const float* nvb = nv + (size_t)b * NN;
    const float* nlb = nl + (size_t)b * NN;
    unsigned* fb = fired + (size_t)b * NN;
    int rowb = i0 + 32 * wr + kg * 4;
    int colb = j0 + 32 * wc + rl;
    #pragma unroll
    for (int fj = 0; fj < 2; ++fj) {
        int gj = colb + 16 * fj;
        float sj = s1b[gj], djv = dvb[gj];
        float nvj = nvb[gj], nlj = nlb[gj];
        #pragma unroll
        for (int fi = 0; fi < 2; ++fi) {
            int gi0 = rowb + 16 * fi;
            #pragma unroll
            for (int r = 0; r < 4; ++r) {
                int gi = gi0 + r;
                if (gj > gi) {
                    float cc = acc[fi][fj][r] - s1b[gi] * sj * invT;
                    float lim = thr2 * dvb[gi] * djv;
                    float nvi = nvb[gi], nli = nlb[gi];
                    float B = nli * nvj + nlj * nvi + 3.0f * nli * nlj
                              + 1e-3f * nvi * nvj;
                    float a = fabsf(cc);
                    float lo = a - B;
                    if (lo > 0.0f && lo * lo > lim) {
                        atomicOr(&fb[gi], 1u);
                    } else if ((a + B) * (a + B) > lim) {
                        unsigned idx = atomicAdd(cnt, 1u);
                        if (idx < LISTCAP)
                            list[idx] = ((unsigned)b << 18) | ((unsigned)gi << 9)
                                        | (unsigned)gj;
                    }
                }
            }
        }
    }
}

// ---------------- kernel B2: exact recompute of borderline pairs ----------------
__global__ __launch_bounds__(256) void cleanup_pairs(
    const float* __restrict__ x, const float* __restrict__ s1,
    const float* __restrict__ dv, const unsigned* __restrict__ cnt,
    const unsigned* __restrict__ list, unsigned* __restrict__ fired) {
    unsigned n = *cnt;
    if (n > LISTCAP) n = LISTCAP;
    int lane = threadIdx.x & 63;
    int gw = (blockIdx.x * 256 + threadIdx.x) >> 6;
    int nw = (gridDim.x * 256) >> 6;
    for (unsigned p = gw; p < n; p += nw) {
        unsigned e = list[p];
        int b = e >> 18, i = (e >> 9) & 511, j = e & 511;
        const float* xb = x + (size_t)b * TT * NN;
        double s = 0.0;
        for (int t = lane; t < TT; t += 64)
            s += (double)xb[(size_t)t * NN + i] * (double)xb[(size_t)t * NN + j];
        #pragma unroll
        for (int o = 32; o > 0; o >>= 1)
            s += __shfl_xor(s, o, 64);
        if (lane == 0) {
            double cov = s - (double)s1[(size_t)b * NN + i]
                             * (double)s1[(size_t)b * NN + j] / (double)TT;
            double lim = (double)THR * (double)THR
                         * (double)dv[(size_t)b * NN + i]
                         * (double)dv[(size_t)b * NN + j];
            if (cov * cov > lim) atomicOr(&fired[(size_t)b * NN + i], 1u);
        }
    }
}

// ---------------- kernel C: finalize mask ----------------
__global__ __launch_bounds__(512) void finalize_mask(
    const unsigned* __restrict__ fired, float* __restrict__ out) {
    int b = blockIdx.x;
    int n = threadIdx.x;
    unsigned f = fired[(size_t)b * NN + n];
    __shared__ int wsum[8];
    unsigned long long m = __ballot(f != 0u);
    int lane = n & 63;
    int w = n >> 6;
    if (lane == 0) wsum[w] = __popcll(m);
    __syncthreads();
    int cnt = 0;
    #pragma unroll
    for (int i = 0; i < 8; ++i) cnt += wsum[i];
    float val = (cnt == 0) ? 1.0f : ((cnt == 1) ? (f ? 1.0f : 0.0f) : 0.0f);
    out[(size_t)b * NN + n] = val;
}

extern "C" void kernel_launch(void* const* d_in, const int* in_sizes, int n_in,
                              void* d_out, int out_size, void* d_ws, size_t ws_size,
                              hipStream_t stream) {
    const float* x = (const float*)d_in[0];
    float* out = (float*)d_out;

    // ws layout (~66 MB)
    ushort* xbf = (ushort*)d_ws;                         // BB*8*32*4096 B = 64 MB
    float* s1 = (float*)(xbf + (size_t)BB * NN * TT);    // B*N
    float* dv = s1 + (size_t)BB * NN;                    // B*N
    float* nv = dv + (size_t)BB * NN;                    // B*N
    float* nl = nv + (size_t)BB * NN;                    // B*N
    unsigned* fired = (unsigned*)(nl + (size_t)BB * NN); // B*N
    unsigned* cnt   = fired + (size_t)BB * NN;           // 16 (padded)
    unsigned* list  = cnt + 16;                          // LISTCAP

    transpose_colsum<<<dim3(BB, 8), 512, 0, stream>>>(x, xbf, s1, dv, nv, nl,
                                                      fired, cnt);
    corr_mfma<<<dim3(2304), 256, 0, stream>>>(xbf, s1, dv, nv, nl, fired, cnt, list);
    cleanup_pairs<<<128, 256, 0, stream>>>(x, s1, dv, cnt, list, fired);
    finalize_mask<<<BB, 512, 0, stream>>>(fired, out);
}